// Round 5
// baseline (126.979 us; speedup 1.0000x reference)
//
#include <hip/hip_runtime.h>

// SIR recurrence, R4: chunked producer/consumer pipeline.
// Model from R1-R3: single wave issues ~1 instr/4.4cyc; ds_write ~13cyc,
// global store ~7.5cyc. => minimize serial-lane instruction count, use
// global stores. Serial lane stores only {u_i, c_i} (4 VALU + 2 stores);
// all output columns are rebuilt bit-exactly by consumer waves one chunk
// behind (barrier-synced, no polling).
//
// FP op order FROZEN (absmax == 0.0 in R1/R2/R3):
//   t  = u*v
//   c  = fmaf(gamma, t, delta)     gamma = w3*w3/1000, delta = fmaf(w3,b3,b3)
//   nu = fmaf(L, u, c)             L = 1 - w2sq - w4sq
//   nv = v - c                     (consumer: fmaf(-1,c,v) == fl(v-c), exact)
//   s1 = fmaf(w2sq, u, s1)
//   s3 = fmaf(w4sq, u, s3)

__global__ __launch_bounds__(256) void sir_kernel(
    const float* __restrict__ x, const float* __restrict__ w2p,
    const float* __restrict__ w3p, const float* __restrict__ b3p,
    const float* __restrict__ w4p, const int* __restrict__ np,
    float* __restrict__ out, float* __restrict__ ws) {
  const int n    = *np;      // 2048
  const int rows = n - 1;    // 2047 output rows
  const int tid  = threadIdx.x;
  const int nch  = (n + 127) >> 7;  // 128-step producer chunks

  float* __restrict__ wsU = ws;      // u_i = input of step i, i in [0,n)
  float* __restrict__ wsC = ws + n;  // c_i

  const float w2 = *w2p, w3 = *w3p, b3 = *b3p, w4 = *w4p;
  const float w2sq  = w2 * w2;
  const float w4sq  = w4 * w4;
  const float L     = 1.0f - w2sq - w4sq;
  const float gamma = (w3 * w3) / 1000.0f;
  const float delta = fmaf(w3, b3, b3);

  // producer state (tid 0 only)
  float u = x[0], v = x[2];

  // consumer chain state (tids 64..66: lane3 = 0,1,2)
  const int lane3 = tid - 64;
  float k = 0.0f, acc = 0.0f;
  const float* __restrict__ src = wsU;
  int colofs = 0;
  if (lane3 == 0)      { k = -1.0f; acc = x[2]; src = wsC; colofs = 2; }
  else if (lane3 == 1) { k = w2sq;  acc = x[1];            colofs = 1; }
  else if (lane3 == 2) { k = w4sq;  acc = x[3];            colofs = 3; }

  for (int ch = 0; ch < nch; ++ch) {
    if (tid == 0) {
      // ---- producer: steps [ch*128, min(n, ch*128+128)) ----
      const int i0 = ch << 7;
      const int i1 = min(n, i0 + 128);
      if (i1 - i0 == 128) {
#pragma unroll 32
        for (int j = 0; j < 128; ++j) {
          const int i = i0 + j;
          const float t = u * v;
          const float c = fmaf(gamma, t, delta);
          wsU[i] = u;                 // global store (cheap, fire-and-forget)
          wsC[i] = c;
          const float nu = fmaf(L, u, c);
          const float nv = v - c;
          u = nu;
          v = nv;
        }
      } else {
        for (int i = i0; i < i1; ++i) {
          const float t = u * v;
          const float c = fmaf(gamma, t, delta);
          wsU[i] = u;
          wsC[i] = c;
          u = fmaf(L, u, c);
          v = v - c;
        }
      }
    } else if (ch > 0) {
      const int cc0 = (ch - 1) << 7;  // completed chunk (visible since last barrier)
      if (lane3 >= 0 && lane3 < 3) {
        // ---- bit-exact serial column chains: v / s1 / s3 ----
        const int e = min(cc0 + 128, rows);
#pragma unroll 16
        for (int i = cc0; i < e; ++i) {
          acc = fmaf(k, src[i], acc);
          out[5 * i + colofs] = acc;
        }
      } else if (tid >= 128) {
        // ---- u column + col-4 zeros; window shifted -1 so wsU[r+1] is
        //      inside the completed chunk (no race with current chunk) ----
        const int r = cc0 - 1 + (tid - 128);
        if (r >= 0 && r < rows) {
          out[5 * r]     = wsU[r + 1];
          out[5 * r + 4] = 0.0f;
        }
      }
    }
    __syncthreads();
  }

  // ---- drain: consume the final chunk (written before last barrier) ----
  {
    const int cc0 = (nch - 1) << 7;
    if (lane3 >= 0 && lane3 < 3) {
      const int e = min(cc0 + 128, rows);
      for (int i = cc0; i < e; ++i) {
        acc = fmaf(k, src[i], acc);
        out[5 * i + colofs] = acc;
      }
    } else if (tid >= 128) {
      const int r = cc0 - 1 + (tid - 128);
      if (r >= 0 && r < rows) {
        out[5 * r]     = wsU[r + 1];
        out[5 * r + 4] = 0.0f;
      }
    }
  }
}

extern "C" void kernel_launch(void* const* d_in, const int* in_sizes, int n_in,
                              void* d_out, int out_size, void* d_ws, size_t ws_size,
                              hipStream_t stream) {
  const float* x   = (const float*)d_in[0];
  const float* w2  = (const float*)d_in[1];
  const float* w3  = (const float*)d_in[2];
  const float* b3  = (const float*)d_in[3];
  const float* w4  = (const float*)d_in[4];
  const int*   n   = (const int*)d_in[5];
  float* out = (float*)d_out;
  float* ws  = (float*)d_ws;  // needs 2*n floats = 16 KB at n=2048
  sir_kernel<<<1, 256, 0, stream>>>(x, w2, w3, b3, w4, n, out, ws);
}

// Round 6
// 100.025 us; speedup vs baseline: 1.2695x; 1.2695x over previous
//
#include <hip/hip_runtime.h>

// SIR recurrence, R5: back to the R1 record structure (plain serial loop,
// 4 global stores/step, helper threads write col-4 zeros then RETIRE —
// no LDS, no barriers; R2-R4 proved those add non-hidden overhead).
// Model discrimination: R1-R4 fit either (a) solo-wave dep-VALU latency
// ~16cyc (chain 3x16=48/step, stores free) or (b) solo-wave issue ~5cyc/instr
// (R1 = 10.5 instr x 5). This round removes ~2.5 instr/step of loop overhead
// via exact-trip specialization (2047 = 23*89, unroll 23, no tail):
//   (b) => ~42.5-43.5 us;  (a) => ~45-46 us unchanged -> next round gambles
//   on the 2-deep-chain reformulation.
//
// FP op order FROZEN (absmax == 0.0 in R1/R2/R3/R4):
//   t  = u*v
//   c  = fmaf(gamma, t, delta)     gamma = w3*w3/1000, delta = fmaf(w3,b3,b3)
//   nu = fmaf(L, u, c)             L = 1 - w2sq - w4sq
//   nv = v - c
//   s1 = fmaf(w2sq, u, s1)
//   s3 = fmaf(w4sq, u, s3)

__global__ __launch_bounds__(256) void sir_kernel(
    const float* __restrict__ x, const float* __restrict__ w2p,
    const float* __restrict__ w3p, const float* __restrict__ b3p,
    const float* __restrict__ w4p, const int* __restrict__ np,
    float* __restrict__ out) {
  const int n = *np;
  const int rows = n - 1;
  const int tid = threadIdx.x;

  if (tid != 0) {
    // col-4 zeros (d_out re-poisoned to 0xAA before every launch).
    // These waves retire quickly and free their SIMD slots.
    for (int i = tid - 1; i < rows; i += 255) out[5 * i + 4] = 0.0f;
    return;
  }

  const float w2 = *w2p, w3 = *w3p, b3 = *b3p, w4 = *w4p;
  const float w2sq  = w2 * w2;
  const float w4sq  = w4 * w4;
  const float L     = 1.0f - w2sq - w4sq;
  const float gamma = (w3 * w3) / 1000.0f;
  const float delta = fmaf(w3, b3, b3);

  float u = x[0], s1 = x[1], v = x[2], s3 = x[3];
  float* __restrict__ p = out;

  if (rows == 2047) {
    // 2047 = 23 * 89: unroll 23 -> exactly 89 iterations, no tail code,
    // store offsets are immediates within each unrolled body (23*20B = 460B).
#pragma unroll 23
    for (int i = 0; i < 2047; ++i) {
      const float t  = u * v;
      const float c  = fmaf(gamma, t, delta);
      const float nu = fmaf(L, u, c);
      const float nv = v - c;
      s1 = fmaf(w2sq, u, s1);
      s3 = fmaf(w4sq, u, s3);
      u = nu;
      v = nv;
      p[0] = nu;
      p[1] = s1;
      p[2] = nv;
      p[3] = s3;
      p += 5;
    }
  } else {
    // generic fallback (same FP sequence) for any other n
#pragma unroll 4
    for (int i = 0; i < rows; ++i) {
      const float t  = u * v;
      const float c  = fmaf(gamma, t, delta);
      const float nu = fmaf(L, u, c);
      const float nv = v - c;
      s1 = fmaf(w2sq, u, s1);
      s3 = fmaf(w4sq, u, s3);
      u = nu;
      v = nv;
      p[0] = nu;
      p[1] = s1;
      p[2] = nv;
      p[3] = s3;
      p += 5;
    }
  }
}

extern "C" void kernel_launch(void* const* d_in, const int* in_sizes, int n_in,
                              void* d_out, int out_size, void* d_ws, size_t ws_size,
                              hipStream_t stream) {
  const float* x   = (const float*)d_in[0];
  const float* w2  = (const float*)d_in[1];
  const float* w3  = (const float*)d_in[2];
  const float* b3  = (const float*)d_in[3];
  const float* w4  = (const float*)d_in[4];
  const int*   n   = (const int*)d_in[5];
  float* out = (float*)d_out;
  sir_kernel<<<1, 256, 0, stream>>>(x, w2, w3, b3, w4, n, out);
}